// Round 9
// baseline (140.800 us; speedup 1.0000x reference)
//
#include <hip/hip_runtime.h>
#include <hip/hip_bf16.h>

// Problem constants
#define BATCH 2
#define TSEQ  2048
#define NEMBD 1024
#define HEADS 16
#define HDIM  64
// GEMM: M = BATCH*TSEQ = 4096, K = NEMBD = 1024, N = 3*NEMBD = 3072

typedef short          bf16x8 __attribute__((ext_vector_type(8)));  // 8 bf16 = 4 VGPRs
typedef float          f32x4  __attribute__((ext_vector_type(4)));
typedef unsigned short u16;

__device__ __forceinline__ u16 f2bf(float f) {
  unsigned int u = __float_as_uint(f);
  u += 0x7fffu + ((u >> 16) & 1u);   // round-to-nearest-even
  return (u16)(u >> 16);
}

// HW packed f32->bf16 (RNE): 2 floats -> 1 u32 in one VALU op
__device__ __forceinline__ unsigned int cvt_pk_bf16(float lo, float hi) {
  unsigned int r;
  asm("v_cvt_pk_bf16_f32 %0, %1, %2" : "=v"(r) : "v"(lo), "v"(hi));
  return r;
}

// async global->LDS, 16B per lane; LDS dest = wave-uniform base + lane*16
__device__ __forceinline__ void gld16(const u16* g, u16* l) {
  __builtin_amdgcn_global_load_lds(
      (const __attribute__((address_space(1))) unsigned int*)g,
      (__attribute__((address_space(3))) unsigned int*)l, 16, 0, 0);
}

// ---------------------------------------------------------------------------
// Merged prep: blocks [0,4096) convert x fp32->bf16; blocks [4096,7168)
// transpose W [1024,3072] fp32 -> Wt [3072,1024] bf16 (32x32 LDS tiles).
__global__ __launch_bounds__(256) void k_prep(const float* __restrict__ x,
                                              u16* __restrict__ xb,
                                              const float* __restrict__ w,
                                              u16* __restrict__ wt) {
  __shared__ float tile[32][33];
  const int b = blockIdx.x;
  const int t = threadIdx.x;
  if (b < 4096) {
    int i = b * 256 + t;
    float4 v = ((const float4*)x)[i];
    ushort4 o;
    o.x = f2bf(v.x); o.y = f2bf(v.y); o.z = f2bf(v.z); o.w = f2bf(v.w);
    ((ushort4*)xb)[i] = o;
  } else {
    const int bt = b - 4096;            // 0..3071
    const int n0 = (bt >> 5) * 32;      // 0..3040
    const int k0 = (bt & 31) * 32;      // 0..992
    const int r  = t >> 3;              // 0..31
    const int c4 = (t & 7) * 4;         // 0,4,..,28
    float4 v = *(const float4*)(w + (size_t)(k0 + r) * 3072 + n0 + c4);
    tile[r][c4 + 0] = v.x; tile[r][c4 + 1] = v.y;
    tile[r][c4 + 2] = v.z; tile[r][c4 + 3] = v.w;
    __syncthreads();
    ushort4 o;
    o.x = f2bf(tile[c4 + 0][r]);
    o.y = f2bf(tile[c4 + 1][r]);
    o.z = f2bf(tile[c4 + 2][r]);
    o.w = f2bf(tile[c4 + 3][r]);
    *(ushort4*)(wt + (size_t)(n0 + r) * 1024 + k0 + c4) = o;
  }
}

// ---------------------------------------------------------------------------
// QKV GEMM (R1-proven winner): C = xb @ Wt^T + bias, 128x128 tile, BK=64,
// global_load_lds (16B) staging with XOR granule swizzle, XCD-aware swizzle.
// Epilogue routes columns: [0,1024)->Q (scaled 0.125*log2e: attn uses exp2),
// [1024,2048)->K, [2048,3072)->V^T ([bh][d][t], cvt_pk-packed x4).
__global__ __launch_bounds__(256, 3) void k_qkv_gemm(
    const u16* __restrict__ xb, const u16* __restrict__ wt,
    const float* __restrict__ bias,
    u16* __restrict__ qb, u16* __restrict__ kbuf, u16* __restrict__ vt) {
  __shared__ __align__(16) u16 As[128 * 64];   // 16 KB
  __shared__ __align__(16) u16 Bs[128 * 64];   // 16 KB

  const int t    = threadIdx.x;
  const int wv   = t >> 6;
  const int lane = t & 63;
  const int m    = lane & 15;
  const int quad = lane >> 4;
  const int lin  = blockIdx.x;
  const int cp   = lin >> 5;                              // 0..23
  const int rp   = ((lin & 7) << 2) | ((lin >> 3) & 3);   // 0..31, XCD-local
  const int row0 = rp * 128;
  const int col0 = cp * 128;
  const int wr   = (wv >> 1) * 64;   // wave row offset in block tile
  const int wc   = (wv & 1) * 64;    // wave col offset

  // staging: wave wv stages rows [wv*32, wv*32+32) in four 8-row DMAs.
  const int sr = wv * 32 + (lane >> 3);
  const int gs = (lane & 7) ^ (sr & 7);
  const u16* ag = xb + (size_t)(row0 + sr) * 1024 + gs * 8;
  const u16* bg = wt + (size_t)(col0 + sr) * 1024 + gs * 8;
  u16* al = As + (wv * 32) * 64;     // wave-uniform LDS base
  u16* bl = Bs + (wv * 32) * 64;

  f32x4 acc[4][4];
  const f32x4 zf = {0.f, 0.f, 0.f, 0.f};
  for (int i = 0; i < 4; ++i)
    for (int j = 0; j < 4; ++j) acc[i][j] = zf;

  for (int kt = 0; kt < 16; ++kt) {
    const int kk = kt * 64;
    __syncthreads();   // previous iter's readers done before DMA overwrite
    gld16(ag + kk,             al);
    gld16(ag + kk +  8 * 1024, al +  8 * 64);
    gld16(ag + kk + 16 * 1024, al + 16 * 64);
    gld16(ag + kk + 24 * 1024, al + 24 * 64);
    gld16(bg + kk,             bl);
    gld16(bg + kk +  8 * 1024, bl +  8 * 64);
    gld16(bg + kk + 16 * 1024, bl + 16 * 64);
    gld16(bg + kk + 24 * 1024, bl + 24 * 64);
    __syncthreads();   // drains vmcnt(0): DMA visible

#pragma unroll
    for (int h = 0; h < 2; ++h) {
      const int g = ((quad + 4 * h) ^ (m & 7)) * 8;
      bf16x8 af[4], bfr[4];
#pragma unroll
      for (int mt = 0; mt < 4; ++mt)
        af[mt] = *(const bf16x8*)(As + (wr + mt * 16 + m) * 64 + g);
#pragma unroll
      for (int nt = 0; nt < 4; ++nt)
        bfr[nt] = *(const bf16x8*)(Bs + (wc + nt * 16 + m) * 64 + g);
#pragma unroll
      for (int mt = 0; mt < 4; ++mt)
#pragma unroll
        for (int nt = 0; nt < 4; ++nt)
          acc[mt][nt] = __builtin_amdgcn_mfma_f32_16x16x32_bf16(
              af[mt], bfr[nt], acc[mt][nt], 0, 0, 0);
    }
  }

  // Epilogue. C row R = row0+wr+mt*16+quad*4+reg ; col Cc = col0+wc+nt*16+m
  const int sec = col0 >> 10;       // uniform per block: 0=Q 1=K 2=V
#pragma unroll
  for (int nt = 0; nt < 4; ++nt) {
    const int Cc = col0 + wc + nt * 16 + m;
    const float bv = bias[Cc];
    const int c = Cc & 1023;
    const int h = c >> 6;
    const int d = c & 63;
#pragma unroll
    for (int mt = 0; mt < 4; ++mt) {
      const int Rbase = row0 + wr + mt * 16 + quad * 4;  // rows Rbase..Rbase+3
      const int bb = Rbase >> 11;
      const int t0 = Rbase & 2047;
      const int bh = bb * HEADS + h;
      if (sec == 0) {
#pragma unroll
        for (int rg = 0; rg < 4; ++rg) {
          // fold 1/sqrt(64) AND log2(e): attn computes p = exp2(s)
          float v = (acc[mt][nt][rg] + bv) * 0.18033688f;
          qb[(size_t)(bh * TSEQ + t0 + rg) * HDIM + d] = f2bf(v);
        }
      } else if (sec == 1) {
#pragma unroll
        for (int rg = 0; rg < 4; ++rg) {
          float v = acc[mt][nt][rg] + bv;
          kbuf[(size_t)(bh * TSEQ + t0 + rg) * HDIM + d] = f2bf(v);
        }
      } else {
        uint2 pk;
        pk.x = cvt_pk_bf16(acc[mt][nt][0] + bv, acc[mt][nt][1] + bv);
        pk.y = cvt_pk_bf16(acc[mt][nt][2] + bv, acc[mt][nt][3] + bv);
        *(uint2*)(vt + (size_t)(bh * HDIM + d) * TSEQ + t0) = pk;
      }
    }
  }
}

// ---------------------------------------------------------------------------
// Flash attention v9: v4 structure (3 blocks/CU, 1024-block grid, QBLK=16)
// + FULL-ITERATION DMA COVER. v4 issued the next-tile DMA after all K/V
// fragment reads (single Kb[2]/Vb[2] arrays: a DMA into buf nb before
// ds_reads of buf b would force a conservative compiler vmcnt wait), so the
// DMA had only the exp/P/PV tail (~300cy) of cover before the end-of-iter
// __syncthreads drained vmcnt(0). Now: FOUR distinct __shared__ arrays
// (Kb0/Kb1/Vb0/Vb1) + key loop unrolled x2 so every buffer ref is static.
// Buffer nb was last read in iter t-1 (barrier-ended), so the DMA for tile
// t+1 issues at the TOP of iter t: ~full iteration of cover, no forced
// waits (distinct objects). Also: exp->exp2 (log2e folded into Q scale),
// cvt_pk P-pack. Everything else identical to v4.
__global__ __launch_bounds__(256, 3) void k_attn(
    const u16* __restrict__ qb, const u16* __restrict__ kbuf,
    const u16* __restrict__ vt, float* __restrict__ out) {
  __shared__ __align__(16) u16 Kb0[4096];   // [row*64 + swizzled col]
  __shared__ __align__(16) u16 Kb1[4096];
  __shared__ __align__(16) u16 Vb0[4096];
  __shared__ __align__(16) u16 Vb1[4096];
  __shared__ __align__(16) u16 pt[4][16 * 72];

  const int t     = threadIdx.x;
  const int wv    = t >> 6;
  const int lane  = t & 63;
  const int m     = lane & 15;
  const int quad  = lane >> 4;
  const int bh    = blockIdx.x & 31;          // bh-fast
  const int qtg   = 31 - (blockIdx.x >> 5);   // long blocks dispatch first
  const int qbase = (qtg * 4 + wv) * 16;
  const int nkt   = qtg + 1;                  // SAME for all 4 waves

  u16* pw = &pt[wv][0];

  // Q fragments (B-operand of S^T), registers for the whole key loop
  const u16* qrow = qb + ((size_t)bh * TSEQ + qbase + m) * HDIM + quad * 8;
  bf16x8 aq0 = *(const bf16x8*)(qrow);
  bf16x8 aq1 = *(const bf16x8*)(qrow + 32);

  // DMA source pointers: wave wv stages rows [wv*16, wv*16+16) of each tile.
  const int sr = wv * 16 + (lane >> 3);
  const int gsk = (lane & 7) ^ (sr & 7);
  const u16* kg = kbuf + ((size_t)bh * TSEQ + sr) * HDIM + gsk * 8;
  const u16* vg = vt + ((size_t)bh * HDIM + sr) * TSEQ + gsk * 8;

  // fragment-read swizzled granule offsets (row r has r&7 == m&7)
  const int swL = (quad ^ (m & 7)) * 8;        // logical granule quad
  const int swH = ((quad + 4) ^ (m & 7)) * 8;  // logical granule quad+4

  f32x4 o[4];
  const f32x4 zf = {0.f, 0.f, 0.f, 0.f};
  for (int nt = 0; nt < 4; ++nt) o[nt] = zf;
  float rsum = 0.f;
  const int qi = qbase + m;            // this lane's q row

  // One key tile: optional DMA of tile TN into (NKL,NVL) issued FIRST
  // (covered by this whole iteration), then S^T, mask, exp2+P, PV.
#define ATTN_TILE(KB, VB, DODMA, TN, NKL, NVL, DOMASK)                        \
  {                                                                           \
    if (DODMA) {                                                              \
      const u16* kgn = kg + (size_t)(TN) * 64 * HDIM;                         \
      const u16* vgn = vg + (TN) * 64;                                        \
      gld16(kgn,            (NKL));                                           \
      gld16(kgn + 8 * HDIM, (NKL) + 8 * 64);                                  \
      gld16(vgn,            (NVL));                                           \
      gld16(vgn + 8 * TSEQ, (NVL) + 8 * 64);                                  \
    }                                                                         \
    f32x4 s[4];                                                               \
    for (int nt = 0; nt < 4; ++nt) s[nt] = zf;                                \
    _Pragma("unroll")                                                         \
    for (int nt = 0; nt < 4; ++nt) {                                          \
      bf16x8 kf = *(const bf16x8*)((KB) + (nt * 16 + m) * 64 + swL);          \
      s[nt] = __builtin_amdgcn_mfma_f32_16x16x32_bf16(kf, aq0, s[nt], 0,0,0); \
    }                                                                         \
    _Pragma("unroll")                                                         \
    for (int nt = 0; nt < 4; ++nt) {                                          \
      bf16x8 kf = *(const bf16x8*)((KB) + (nt * 16 + m) * 64 + swH);          \
      s[nt] = __builtin_amdgcn_mfma_f32_16x16x32_bf16(kf, aq1, s[nt], 0,0,0); \
    }                                                                         \
    bf16x8 vfL[4], vfH[4];                                                    \
    _Pragma("unroll")                                                         \
    for (int nt = 0; nt < 4; ++nt) {                                          \
      vfL[nt] = *(const bf16x8*)((VB) + (nt * 16 + m) * 64 + swL);            \
      vfH[nt] = *(const bf16x8*)((VB) + (nt * 16 + m) * 64 + swH);            \
    }                                                                         \
    if (DOMASK) {                                                             \
      const int kb_ = (nkt - 1) * 64 + quad * 4;                              \
      _Pragma("unroll")                                                       \
      for (int nt = 0; nt < 4; ++nt)                                          \
        _Pragma("unroll")                                                     \
        for (int rg = 0; rg < 4; ++rg)                                        \
          if (kb_ + nt * 16 + rg > qi) s[nt][rg] = -1e30f;                    \
    }                                                                         \
    _Pragma("unroll")                                                         \
    for (int nt = 0; nt < 4; ++nt) {                                          \
      float p0 = exp2f(s[nt][0]), p1 = exp2f(s[nt][1]);                       \
      float p2 = exp2f(s[nt][2]), p3 = exp2f(s[nt][3]);                       \
      rsum += (p0 + p1) + (p2 + p3);                                          \
      uint2 pk;                                                               \
      pk.x = cvt_pk_bf16(p0, p1);                                             \
      pk.y = cvt_pk_bf16(p2, p3);                                             \
      *(uint2*)(pw + m * 72 + nt * 16 + quad * 4) = pk;                       \
    }                                                                         \
    bf16x8 bp0 = *(const bf16x8*)(pw + m * 72 + quad * 8);                    \
    bf16x8 bp1 = *(const bf16x8*)(pw + m * 72 + 32 + quad * 8);               \
    _Pragma("unroll")                                                         \
    for (int nt = 0; nt < 4; ++nt)                                            \
      o[nt] = __builtin_amdgcn_mfma_f32_16x16x32_bf16(vfL[nt], bp0, o[nt],    \
                                                      0, 0, 0);               \
    _Pragma("unroll")                                                         \
    for (int nt = 0; nt < 4; ++nt)                                            \
      o[nt] = __builtin_amdgcn_mfma_f32_16x16x32_bf16(vfH[nt], bp1, o[nt],    \
                                                      0, 0, 0);               \
  }

  // preload tile 0 into buffer 0
  gld16(kg,            &Kb0[wv * 16 * 64]);
  gld16(kg + 8 * HDIM, &Kb0[wv * 16 * 64 + 8 * 64]);
  gld16(vg,            &Vb0[wv * 16 * 64]);
  gld16(vg + 8 * TSEQ, &Vb0[wv * 16 * 64 + 8 * 64]);
  __syncthreads();                     // vmcnt(0) drain + barrier

  int kt = 0;
  for (; kt + 1 < nkt; kt += 2) {
    // tile kt (buf0); DMA tile kt+1 -> buf1 at top (always exists here)
    ATTN_TILE(&Kb0[0], &Vb0[0], true, kt + 1,
              &Kb1[wv * 16 * 64], &Vb1[wv * 16 * 64], false)
    __syncthreads();
    // tile kt+1 (buf1); DMA tile kt+2 -> buf0 if it exists; mask if last
    ATTN_TILE(&Kb1[0], &Vb1[0], (kt + 2 < nkt), kt + 2,
              &Kb0[wv * 16 * 64], &Vb0[wv * 16 * 64], (kt + 2 >= nkt))
    __syncthreads();
  }
  if (kt < nkt) {
    // odd nkt tail: tile kt == nkt-1 in buf0, mask, no DMA
    ATTN_TILE(&Kb0[0], &Vb0[0], false, 0,
              &Kb1[wv * 16 * 64], &Vb1[wv * 16 * 64], true)
  }
#undef ATTN_TILE

  // l reduction: lanes {m, m+16, m+32, m+48} hold the same q row
  rsum += __shfl_xor(rsum, 16);
  rsum += __shfl_xor(rsum, 32);
  const float inv = 1.0f / rsum;

  // epilogue: O^T C-layout -> out[b][t][h*64 + nt*16 + quad*4 + rg], float4
  const int bb = bh >> 4;
  const int h  = bh & 15;
  float* ob = out + ((size_t)(bb * TSEQ + qi) * NEMBD + h * HDIM + quad * 4);
#pragma unroll
  for (int nt = 0; nt < 4; ++nt) {
    float4 st;
    st.x = o[nt][0] * inv; st.y = o[nt][1] * inv;
    st.z = o[nt][2] * inv; st.w = o[nt][3] * inv;
    *(float4*)(ob + nt * 16) = st;
  }
}

// ---------------------------------------------------------------------------
extern "C" void kernel_launch(void* const* d_in, const int* in_sizes, int n_in,
                              void* d_out, int out_size, void* d_ws, size_t ws_size,
                              hipStream_t stream) {
  (void)in_sizes; (void)n_in; (void)out_size; (void)ws_size;
  const float* x    = (const float*)d_in[0];
  const float* W    = (const float*)d_in[1];
  const float* bqkv = (const float*)d_in[2];
  float* out = (float*)d_out;

  // ws layout (u16 elements): qb | kbuf | vt | xb | wt  -> ~38 MB total
  u16* ws   = (u16*)d_ws;
  u16* qb   = ws;                       // 2*16*2048*64 = 4194304
  u16* kbuf = ws + 4194304;
  u16* vt   = ws + 2 * 4194304;
  u16* xb   = ws + 3 * 4194304;         // 4096*1024 = 4194304
  u16* wt   = ws + 4 * 4194304;         // 3072*1024 = 3145728

  hipLaunchKernelGGL(k_prep, dim3(7168), dim3(256), 0, stream, x, xb, W, wt);
  hipLaunchKernelGGL(k_qkv_gemm, dim3(768), dim3(256), 0, stream,
                     xb, wt, bqkv, qb, kbuf, vt);
  hipLaunchKernelGGL(k_attn, dim3(1024), dim3(256), 0, stream,
                     qb, kbuf, vt, out);
}